// Round 12
// baseline (355.976 us; speedup 1.0000x reference)
//
#include <hip/hip_runtime.h>
#include <math.h>

typedef __bf16 bf16x8 __attribute__((ext_vector_type(8)));
typedef float f32x4 __attribute__((ext_vector_type(4)));

// ---------- helpers ----------

__device__ __forceinline__ unsigned short f2bf(float f) {
    unsigned int u = __float_as_uint(f);
    u += 0x7FFFu + ((u >> 16) & 1u);   // round-to-nearest-even
    return (unsigned short)(u >> 16);
}

// fast logcosh via HW v_exp/v_log (TRANS pipe). abs err ~1e-6/elem, budget 0.02.
__device__ __forceinline__ float logcosh_fast(float v) {
    float a = fabsf(v);
    float t = __expf(-2.0f * a);
    return a + (__logf(1.0f + t) - 0.6931471805599453f);
}

// DPP row_shr add; after shr 1,2,4,8 lane 15 of each 16-lane row holds row sum.
template <int CTRL>
__device__ __forceinline__ float dppadd(float x) {
    int y = __builtin_amdgcn_update_dpp(0, __float_as_int(x), CTRL, 0xf, 0xf, true);
    return x + __int_as_float(y);
}

__device__ __forceinline__ void gload_lds16(const void* g, void* l) {
    __builtin_amdgcn_global_load_lds(
        (__attribute__((address_space(1))) void*)(void*)g,
        (__attribute__((address_space(3))) void*)l, 16, 0, 0);
}

#define SBAR()  __builtin_amdgcn_s_barrier()
#define SCHED() __builtin_amdgcn_sched_barrier(0)

// ---------- kernel 1: invert permutations ----------
__global__ __launch_bounds__(256) void k_invert(const int* __restrict__ perms,
                                                int* __restrict__ inv) {
    int t = blockIdx.x * 256 + threadIdx.x;
    int g = t >> 10, n = t & 1023;
    inv[(g << 10) + perms[t]] = n;
}

// ---------- kernel 2: bT[j][k] = bf16(W[inv[g][k]][f]), j = g*16+f ----------
__global__ __launch_bounds__(256) void k_build_bt(const float* __restrict__ W,
                                                  const int* __restrict__ inv,
                                                  unsigned short* __restrict__ bT) {
    int j = blockIdx.x;
    int g = j >> 4, f = j & 15;
    const int* invg = inv + (g << 10);
    size_t rowbase = (size_t)j << 10;
#pragma unroll
    for (int i = 0; i < 4; ++i) {
        int k = (i << 8) + threadIdx.x;
        int n = invg[k];
        bT[rowbase + k] = f2bf(W[(n << 4) + f]);
    }
}

// ---------- kernel 3: x -> bf16, out[row] = v_bias * sum(x[row]) ----------
__global__ __launch_bounds__(256) void k_convert(const float* __restrict__ x,
                                                 const float* __restrict__ vb,
                                                 unsigned short* __restrict__ xb,
                                                 float* __restrict__ out) {
    int row = blockIdx.x, tid = threadIdx.x;
    size_t base = ((size_t)row << 10) + (tid << 2);
    float4 v = *reinterpret_cast<const float4*>(x + base);
    ushort4 h;
    h.x = f2bf(v.x); h.y = f2bf(v.y); h.z = f2bf(v.z); h.w = f2bf(v.w);
    *reinterpret_cast<ushort4*>(xb + base) = h;
    float s = v.x + v.y + v.z + v.w;
#pragma unroll
    for (int off = 32; off > 0; off >>= 1) s += __shfl_down(s, off);
    __shared__ float ls[4];
    if ((tid & 63) == 0) ls[tid >> 6] = s;
    __syncthreads();
    if (tid == 0) out[row] = vb[0] * (ls[0] + ls[1] + ls[2] + ls[3]);
}

// ---------- kernel 4: PERSISTENT 256x256 GEMM, 4 fused passes + reg-only epilogue.
// 256 blocks (1/CU), each: fixed col-block, 4 row-blocks sequentially; the
// 64-tile pipeline never drains across pass boundaries (tiles 14,15 of pass p
// stage tiles 0,1 of pass p+1; uniform vmcnt(8) ledger). Pass epilogue is
// register-only (DPP reduce + direct global f32x4 stores of per-(cbx,wn)
// partials) -> overlaps in-flight stages, no LDS/barrier. B panel (512KB,
// fixed) L2-resident after pass 0. Schedule per tile = R7 m-walk (proven 158us).

#define MFMA_M(MM)                                                               \
    _Pragma("unroll") for (int k_ = 0; k_ < 2; ++k_)                             \
    _Pragma("unroll") for (int n_ = 0; n_ < 4; ++n_)                             \
        acc[MM][n_] = __builtin_amdgcn_mfma_f32_16x16x32_bf16(                   \
            aF[MM][k_], bF[n_][k_], acc[MM][n_], 0, 0, 0);

// stage instr i (of 4) for one 256x64 tile: 512 chunks of 16B, 512 threads
__device__ __forceinline__ void stage_i(unsigned short* dst, const unsigned short* src,
                                        int voff, int i, int wv) {
    gload_lds16(src + voff, dst + (((i << 9) + (wv << 6)) << 3));
}

template <bool STAGE, int VM>
__device__ __forceinline__ void tile_iter(
    const unsigned short* Ap, const unsigned short* Bp,   // read bufs (= stage dst)
    unsigned short* AsD, unsigned short* BsD,
    const unsigned short* xsrc, const unsigned short* bsrc,   // t+2 global srcs
    f32x4 (&acc)[8][4], const int (&vs)[4],
    int aRow, int bRow, int po0, int po1, int wv) {
    bf16x8 aF[8][2], bF[4][2];

    // tile start: 8 bF reads then 4 aF reads (issue order = ledger order)
#pragma unroll
    for (int n = 0; n < 4; ++n) {
        bF[n][0] = *reinterpret_cast<const bf16x8*>(Bp + bRow + po0 + n * 1024);
        bF[n][1] = *reinterpret_cast<const bf16x8*>(Bp + bRow + po1 + n * 1024);
    }
#pragma unroll
    for (int m = 0; m < 2; ++m) {
        aF[m][0] = *reinterpret_cast<const bf16x8*>(Ap + aRow + po0 + m * 1024);
        aF[m][1] = *reinterpret_cast<const bf16x8*>(Ap + aRow + po1 + m * 1024);
    }
    SCHED();

    // phases 0..5: read ahead 2 frags, wait lgkm(4) (aF[m] done), 8 MFMA
#pragma unroll
    for (int m = 0; m < 6; ++m) {
        aF[m + 2][0] = *reinterpret_cast<const bf16x8*>(Ap + aRow + po0 + (m + 2) * 1024);
        aF[m + 2][1] = *reinterpret_cast<const bf16x8*>(Ap + aRow + po1 + (m + 2) * 1024);
        SCHED();
        asm volatile("s_waitcnt lgkmcnt(4)" ::: "memory");
        SCHED();
        __builtin_amdgcn_s_setprio(1);
        MFMA_M(m)
        __builtin_amdgcn_s_setprio(0);
        SCHED();
    }

    // all 24 reads of this buffer complete in every wave -> stages into it safe
    asm volatile("s_waitcnt lgkmcnt(0)" ::: "memory");
    SCHED();
    SBAR();

    // phase 6: stage A(t+2); MFMA m=6
    if (STAGE) {
#pragma unroll
        for (int i = 0; i < 4; ++i) stage_i(AsD, xsrc, vs[i], i, wv);
    }
    SCHED();
    __builtin_amdgcn_s_setprio(1);
    MFMA_M(6)
    __builtin_amdgcn_s_setprio(0);
    SCHED();

    // phase 7: stage B(t+2); MFMA m=7; counted vmcnt; barrier
    if (STAGE) {
#pragma unroll
        for (int i = 0; i < 4; ++i) stage_i(BsD, bsrc, vs[i], i, wv);
    }
    SCHED();
    __builtin_amdgcn_s_setprio(1);
    MFMA_M(7)
    __builtin_amdgcn_s_setprio(0);
    SCHED();
    if (VM == 8)      { asm volatile("s_waitcnt vmcnt(8)" ::: "memory"); }
    else if (VM == 0) { asm volatile("s_waitcnt vmcnt(0)" ::: "memory"); }
    SCHED();
    SBAR();
}

__global__ __launch_bounds__(512, 2) void k_gemm(const unsigned short* __restrict__ xb,
                                                 const unsigned short* __restrict__ bT,
                                                 const float* __restrict__ bias,
                                                 float* __restrict__ partial, int B) {
    __shared__ unsigned short As[2][256 * 64];
    __shared__ unsigned short Bs[2][256 * 64];

    const int tid = threadIdx.x;
    const int lane = tid & 63;
    const int wv = tid >> 6;           // 0..7
    const int wm = wv >> 2;            // 0..1  (M half)
    const int wn = wv & 3;             // 0..3  (N quarter)
    const int lr = lane & 15;
    const int lk = lane >> 4;

    // bid -> (cbx, chain): each XCD (bid%8) covers 4 cbx x 8 chains.
    const int bid = blockIdx.x;        // 256 blocks
    const int x8 = bid & 7, u = bid >> 3;
    const int cbx = (x8 & 3) * 4 + (u & 3);          // 0..15 (fixed per block)
    const int chain = (x8 >> 2) * 8 + (u >> 2);      // 0..15
    const int j0 = cbx << 8;

    const unsigned short* bbase = bT + ((size_t)j0 << 10);
    const unsigned short* xcur = xb + ((size_t)(chain << 10) << 10);  // rowb=chain*4
    const unsigned short* xnext = xcur + (256 << 10);                 // next pass

    // per-wave LDS read bases (short units); +m*1024 imm offsets
    const int aRow = (wm * 128 + lr) * 64;
    const int bRow = (wn * 64 + lr) * 64;
    const int po0 = (lk ^ (lr & 7)) * 8;
    const int po1 = ((4 + lk) ^ (lr & 7)) * 8;

    // per-thread stage source voffsets (shorts); instr i covers chunks i*512+tid
    int vs[4];
#pragma unroll
    for (int i = 0; i < 4; ++i) {
        int cc = (i << 9) + tid;
        int r = cc >> 3;
        int cs = (cc & 7) ^ (r & 7);
        vs[i] = (r << 10) + (cs << 3);
    }

    f32x4 acc[8][4];
#pragma unroll
    for (int m = 0; m < 8; ++m)
#pragma unroll
        for (int n = 0; n < 4; ++n)
            acc[m][n] = {0.f, 0.f, 0.f, 0.f};

    // ---- prologue (once): stage tile0(A,B) + tile1(A,B); wait tile0; SBAR ----
#pragma unroll
    for (int i = 0; i < 4; ++i) stage_i(&As[0][0], xcur, vs[i], i, wv);
#pragma unroll
    for (int i = 0; i < 4; ++i) stage_i(&Bs[0][0], bbase, vs[i], i, wv);
#pragma unroll
    for (int i = 0; i < 4; ++i) stage_i(&As[1][0], xcur + 64, vs[i], i, wv);
#pragma unroll
    for (int i = 0; i < 4; ++i) stage_i(&Bs[1][0], bbase + 64, vs[i], i, wv);
    asm volatile("s_waitcnt vmcnt(8)" ::: "memory");   // tile0 landed
    SCHED();
    SBAR();

    const float bv = bias[lr];
    int row0 = chain << 10;            // rowb*256 = chain*1024

    // ---- 4 fused passes; pipeline continuous across boundaries ----
    for (int p = 0; p < 4; ++p) {
        const bool last = (p == 3);

        // t = 0..13: steady, stage tile t+2 of THIS pass
        for (int tt = 0; tt < 7; ++tt) {
            const int t0 = tt * 2;
            tile_iter<true, 8>(&As[0][0], &Bs[0][0], &As[0][0], &Bs[0][0],
                               xcur + ((t0 + 2) << 6), bbase + ((t0 + 2) << 6),
                               acc, vs, aRow, bRow, po0, po1, wv);
            tile_iter<true, 8>(&As[1][0], &Bs[1][0], &As[1][0], &Bs[1][0],
                               xcur + ((t0 + 3) << 6), bbase + ((t0 + 3) << 6),
                               acc, vs, aRow, bRow, po0, po1, wv);
        }
        // t = 14,15: stage tiles 0,1 of NEXT pass (or drain on last pass)
        if (!last) {
            tile_iter<true, 8>(&As[0][0], &Bs[0][0], &As[0][0], &Bs[0][0],
                               xnext, bbase, acc, vs, aRow, bRow, po0, po1, wv);
            tile_iter<true, 8>(&As[1][0], &Bs[1][0], &As[1][0], &Bs[1][0],
                               xnext + 64, bbase + 64, acc, vs, aRow, bRow, po0, po1, wv);
        } else {
            tile_iter<false, 0>(&As[0][0], &Bs[0][0], &As[0][0], &Bs[0][0],
                                xcur, bbase, acc, vs, aRow, bRow, po0, po1, wv);
            tile_iter<false, -1>(&As[1][0], &Bs[1][0], &As[1][0], &Bs[1][0],
                                 xcur, bbase, acc, vs, aRow, bRow, po0, po1, wv);
        }

        // ---- register-only epilogue: logcosh + DPP reduce + direct stores ----
        // (no LDS, no barrier: overlaps the in-flight next-pass stages)
        {
            float* pdst = partial + (size_t)(cbx * 4 + wn) * B + row0 + wm * 128;
#pragma unroll
            for (int m = 0; m < 8; ++m) {
                f32x4 sv;
#pragma unroll
                for (int r = 0; r < 4; ++r) {
                    float s = 0.f;
#pragma unroll
                    for (int n = 0; n < 4; ++n) s += logcosh_fast(acc[m][n][r] + bv);
                    s = dppadd<0x111>(s);
                    s = dppadd<0x112>(s);
                    s = dppadd<0x114>(s);
                    s = dppadd<0x118>(s);
                    sv[r] = s;
                }
                if (lr == 15)
                    *reinterpret_cast<f32x4*>(pdst + m * 16 + lk * 4) = sv;
            }
        }
        // reset acc for next pass
#pragma unroll
        for (int m = 0; m < 8; ++m)
#pragma unroll
            for (int n = 0; n < 4; ++n)
                acc[m][n] = {0.f, 0.f, 0.f, 0.f};

        xcur = xnext;
        xnext += (256 << 10);
        row0 += 256;
    }
}

// ---------- kernel 5: out[b] += sum_s partial[s][b], s = 0..63 ----------
__global__ __launch_bounds__(256) void k_final(const float* __restrict__ partial,
                                               float* __restrict__ out, int ns, int B) {
    int b = blockIdx.x * 256 + threadIdx.x;
    float s = out[b];
    for (int c = 0; c < ns; ++c) s += partial[(size_t)c * B + b];
    out[b] = s;
}

// ---------- launch ----------
extern "C" void kernel_launch(void* const* d_in, const int* in_sizes, int n_in,
                              void* d_out, int out_size, void* d_ws, size_t ws_size,
                              hipStream_t stream) {
    const float* x      = (const float*)d_in[0];  // [B,1024]
    const float* W      = (const float*)d_in[1];  // [1024,16]
    const float* bias   = (const float*)d_in[2];  // [16]
    const float* v_bias = (const float*)d_in[3];  // [1]
    const int*   perms  = (const int*)d_in[4];    // [G,1024]
    float* out = (float*)d_out;

    const int N  = 1024;
    const int B  = in_sizes[0] / N;   // 16384
    const int G  = in_sizes[4] / N;   // 256
    const int GF = G * 16;            // 4096
    const int NS = (GF / 256) * 4;    // 64 partial slices

    char* w = (char*)d_ws;
    unsigned short* xb = (unsigned short*)w;                           // B*N*2   = 32 MB
    unsigned short* bT = (unsigned short*)(w + (size_t)B * N * 2);     // GF*N*2  = 8 MB
    int* inv = (int*)(w + (size_t)B * N * 2 + (size_t)GF * N * 2);     // G*N*4   = 1 MB
    float* partial = (float*)(w + (size_t)B * N * 2 + (size_t)GF * N * 2
                              + (size_t)G * N * 4);                    // NS*B*4  = 4 MB

    k_invert<<<G * N / 256, 256, 0, stream>>>(perms, inv);
    k_build_bt<<<GF, 256, 0, stream>>>(W, inv, bT);
    k_convert<<<B, 256, 0, stream>>>(x, v_bias, xb, out);
    k_gemm<<<256, 512, 0, stream>>>(xb, bT, bias, partial, B);
    k_final<<<B / 256, 256, 0, stream>>>(partial, out, NS, B);
}

// Round 13
// 205.662 us; speedup vs baseline: 1.7309x; 1.7309x over previous
//
#include <hip/hip_runtime.h>
#include <math.h>

typedef __bf16 bf16x8 __attribute__((ext_vector_type(8)));
typedef float f32x16 __attribute__((ext_vector_type(16)));

// ---------- helpers ----------

__device__ __forceinline__ unsigned short f2bf(float f) {
    unsigned int u = __float_as_uint(f);
    u += 0x7FFFu + ((u >> 16) & 1u);   // round-to-nearest-even
    return (unsigned short)(u >> 16);
}

// fast logcosh via HW v_exp/v_log (TRANS pipe). abs err ~1e-6/elem, budget 0.02.
__device__ __forceinline__ float logcosh_fast(float v) {
    float a = fabsf(v);
    float t = __expf(-2.0f * a);
    return a + (__logf(1.0f + t) - 0.6931471805599453f);
}

// DPP add; 0x111/0x112/0x114/0x118 = row_shr 1/2/4/8, 0x142 = row_bcast15.
template <int CTRL>
__device__ __forceinline__ float dppadd(float x) {
    int y = __builtin_amdgcn_update_dpp(0, __float_as_int(x), CTRL, 0xf, 0xf, true);
    return x + __int_as_float(y);
}

__device__ __forceinline__ void gload_lds16(const void* g, void* l) {
    __builtin_amdgcn_global_load_lds(
        (__attribute__((address_space(1))) void*)(void*)g,
        (__attribute__((address_space(3))) void*)l, 16, 0, 0);
}

#define SBAR()  __builtin_amdgcn_s_barrier()
#define SCHED() __builtin_amdgcn_sched_barrier(0)

// ---------- kernel 1: invert permutations ----------
__global__ __launch_bounds__(256) void k_invert(const int* __restrict__ perms,
                                                int* __restrict__ inv) {
    int t = blockIdx.x * 256 + threadIdx.x;
    int g = t >> 10, n = t & 1023;
    inv[(g << 10) + perms[t]] = n;
}

// ---------- kernel 2: bT[j][k] = bf16(W[inv[g][k]][f]), j = g*16+f ----------
__global__ __launch_bounds__(256) void k_build_bt(const float* __restrict__ W,
                                                  const int* __restrict__ inv,
                                                  unsigned short* __restrict__ bT) {
    int j = blockIdx.x;
    int g = j >> 4, f = j & 15;
    const int* invg = inv + (g << 10);
    size_t rowbase = (size_t)j << 10;
#pragma unroll
    for (int i = 0; i < 4; ++i) {
        int k = (i << 8) + threadIdx.x;
        int n = invg[k];
        bT[rowbase + k] = f2bf(W[(n << 4) + f]);
    }
}

// ---------- kernel 3: x -> bf16, out[row] = v_bias * sum(x[row]) ----------
__global__ __launch_bounds__(256) void k_convert(const float* __restrict__ x,
                                                 const float* __restrict__ vb,
                                                 unsigned short* __restrict__ xb,
                                                 float* __restrict__ out) {
    int row = blockIdx.x, tid = threadIdx.x;
    size_t base = ((size_t)row << 10) + (tid << 2);
    float4 v = *reinterpret_cast<const float4*>(x + base);
    ushort4 h;
    h.x = f2bf(v.x); h.y = f2bf(v.y); h.z = f2bf(v.z); h.w = f2bf(v.w);
    *reinterpret_cast<ushort4*>(xb + base) = h;
    float s = v.x + v.y + v.z + v.w;
#pragma unroll
    for (int off = 32; off > 0; off >>= 1) s += __shfl_down(s, off);
    __shared__ float ls[4];
    if ((tid & 63) == 0) ls[tid >> 6] = s;
    __syncthreads();
    if (tid == 0) out[row] = vb[0] * (ls[0] + ls[1] + ls[2] + ls[3]);
}

// ---------- kernel 4: 256x256 GEMM, 32x32x16 MFMA, R7 m-walk schedule ----------
// 8 waves (2m x 4n), per-wave 128x64 = 4 mb x 2 nb blocks of 32x32. 16 K-tiles
// BK=64 (4 ksteps of 16). Per tile (2 barriers):
//   front: 8 bF reads + 4 aF(mb0); mb=0..2: {prefetch aF(mb+1) (4); lgkm(4);
//   8 MFMA}; lgkm(0); SBAR; ph6: stage A(t+2) + 4 MFMA (mb3,nb0);
//   ph7: stage B(t+2) + 4 MFMA (mb3,nb1); vmcnt(8); SBAR.
// 32x32 MFMA: 34 cyc/instr -> 271-cyc clusters/SIMD hide the co-wave's reads.
// Frag: lane row = lane&31, octet = 2s + (lane>>5); swizzle pos = oct^(row&7).
// C/D: col=lane&31, row=(reg&3)+8*(reg>>2)+4*(lane>>5)  [m74/m101 verified].

// stage instr i (of 4) for one 256x64 tile: 512 chunks of 16B, 512 threads
__device__ __forceinline__ void stage_i(unsigned short* dst, const unsigned short* src,
                                        int voff, int i, int wv) {
    gload_lds16(src + voff, dst + (((i << 9) + (wv << 6)) << 3));
}

template <bool STAGE, int VM>
__device__ __forceinline__ void tile32(
    const unsigned short* Ap, const unsigned short* Bp,   // read bufs (= stage dst)
    unsigned short* AsD, unsigned short* BsD,
    const unsigned short* xsrc, const unsigned short* bsrc,
    f32x16 (&acc)[4][2], const int (&vs)[4],
    int aBase, int bBase, const int (&po)[4], int wv) {
    bf16x8 aF[2][4], bF[2][4];

    // front: 8 bF then 4 aF(mb0) (issue order = ledger order)
#pragma unroll
    for (int nb = 0; nb < 2; ++nb)
#pragma unroll
        for (int s = 0; s < 4; ++s)
            bF[nb][s] = *reinterpret_cast<const bf16x8*>(Bp + bBase + nb * 2048 + po[s]);
#pragma unroll
    for (int s = 0; s < 4; ++s)
        aF[0][s] = *reinterpret_cast<const bf16x8*>(Ap + aBase + po[s]);
    SCHED();

    // mb = 0..2: prefetch aF(mb+1), lgkm(4) -> aF(mb) ready, 8 MFMA
#pragma unroll
    for (int mb = 0; mb < 3; ++mb) {
#pragma unroll
        for (int s = 0; s < 4; ++s)
            aF[(mb + 1) & 1][s] = *reinterpret_cast<const bf16x8*>(
                Ap + aBase + (mb + 1) * 2048 + po[s]);
        SCHED();
        asm volatile("s_waitcnt lgkmcnt(4)" ::: "memory");
        SCHED();
        __builtin_amdgcn_s_setprio(1);
#pragma unroll
        for (int s = 0; s < 4; ++s)
#pragma unroll
            for (int nb = 0; nb < 2; ++nb)
                acc[mb][nb] = __builtin_amdgcn_mfma_f32_32x32x16_bf16(
                    aF[mb & 1][s], bF[nb][s], acc[mb][nb], 0, 0, 0);
        __builtin_amdgcn_s_setprio(0);
        SCHED();
    }
    asm volatile("s_waitcnt lgkmcnt(0)" ::: "memory");
    SCHED();
    SBAR();   // all waves' reads of this buffer drained -> stages into it safe

    // ph6: stage A(t+2); MFMA (mb3, nb0)
    if (STAGE) {
#pragma unroll
        for (int i = 0; i < 4; ++i) stage_i(AsD, xsrc, vs[i], i, wv);
    }
    SCHED();
    __builtin_amdgcn_s_setprio(1);
#pragma unroll
    for (int s = 0; s < 4; ++s)
        acc[3][0] = __builtin_amdgcn_mfma_f32_32x32x16_bf16(
            aF[1][s], bF[0][s], acc[3][0], 0, 0, 0);
    __builtin_amdgcn_s_setprio(0);
    SCHED();

    // ph7: stage B(t+2); MFMA (mb3, nb1); counted vmcnt; SBAR
    if (STAGE) {
#pragma unroll
        for (int i = 0; i < 4; ++i) stage_i(BsD, bsrc, vs[i], i, wv);
    }
    SCHED();
    __builtin_amdgcn_s_setprio(1);
#pragma unroll
    for (int s = 0; s < 4; ++s)
        acc[3][1] = __builtin_amdgcn_mfma_f32_32x32x16_bf16(
            aF[1][s], bF[1][s], acc[3][1], 0, 0, 0);
    __builtin_amdgcn_s_setprio(0);
    SCHED();
    if (VM == 8)      { asm volatile("s_waitcnt vmcnt(8)" ::: "memory"); }
    else if (VM == 0) { asm volatile("s_waitcnt vmcnt(0)" ::: "memory"); }
    SCHED();
    SBAR();
}

__global__ __launch_bounds__(512, 2) void k_gemm(const unsigned short* __restrict__ xb,
                                                 const unsigned short* __restrict__ bT,
                                                 const float* __restrict__ bias,
                                                 float* __restrict__ partial, int B) {
    __shared__ unsigned short As[2][256 * 64];
    __shared__ unsigned short Bs[2][256 * 64];

    const int tid = threadIdx.x;
    const int lane = tid & 63;
    const int wv = tid >> 6;           // 0..7
    const int wm = wv >> 2;            // 0..1  (M half)
    const int wn = wv & 3;             // 0..3  (N quarter)
    const int la31 = lane & 31;
    const int hi = lane >> 5;

    // XCD-bijective swizzle (nwg = 1024, % 8 == 0)
    const int fid = blockIdx.y * gridDim.x + blockIdx.x;
    const int cpx = (gridDim.x * gridDim.y) >> 3;
    const int swz = (fid & 7) * cpx + (fid >> 3);
    const int cbx = swz & 15;          // col block (0..15)
    const int row0 = (swz >> 4) << 8;  // row block * 256
    const int j0 = cbx << 8;

    const unsigned short* xbase = xb + ((size_t)row0 << 10);
    const unsigned short* bbase = bT + ((size_t)j0 << 10);

    // per-lane LDS read bases/offsets (short units)
    const int aBase = (wm * 128 + la31) * 64;
    const int bBase = (wn * 64 + la31) * 64;
    int po[4];
#pragma unroll
    for (int s = 0; s < 4; ++s) po[s] = ((2 * s + hi) ^ (la31 & 7)) * 8;

    // per-thread stage source voffsets (shorts); instr i covers chunks i*512+tid
    int vs[4];
#pragma unroll
    for (int i = 0; i < 4; ++i) {
        int cc = (i << 9) + tid;
        int r = cc >> 3;
        int cs = (cc & 7) ^ (r & 7);
        vs[i] = (r << 10) + (cs << 3);
    }

    f32x16 acc[4][2];
#pragma unroll
    for (int mb = 0; mb < 4; ++mb)
#pragma unroll
        for (int nb = 0; nb < 2; ++nb)
#pragma unroll
            for (int i = 0; i < 16; ++i) acc[mb][nb][i] = 0.f;

    // ---- prologue: stage tile0(A,B) + tile1(A,B); wait tile0; SBAR ----
#pragma unroll
    for (int i = 0; i < 4; ++i) stage_i(&As[0][0], xbase, vs[i], i, wv);
#pragma unroll
    for (int i = 0; i < 4; ++i) stage_i(&Bs[0][0], bbase, vs[i], i, wv);
#pragma unroll
    for (int i = 0; i < 4; ++i) stage_i(&As[1][0], xbase + 64, vs[i], i, wv);
#pragma unroll
    for (int i = 0; i < 4; ++i) stage_i(&Bs[1][0], bbase + 64, vs[i], i, wv);
    asm volatile("s_waitcnt vmcnt(8)" ::: "memory");   // tile0 landed
    SCHED();
    SBAR();

    // ---- main loop: tiles 0..13 steady (stage t+2, vmcnt(8)); 14,15 tail ----
    for (int tt = 0; tt < 7; ++tt) {
        const int t0 = tt * 2;
        tile32<true, 8>(&As[0][0], &Bs[0][0], &As[0][0], &Bs[0][0],
                        xbase + ((t0 + 2) << 6), bbase + ((t0 + 2) << 6),
                        acc, vs, aBase, bBase, po, wv);
        tile32<true, 8>(&As[1][0], &Bs[1][0], &As[1][0], &Bs[1][0],
                        xbase + ((t0 + 3) << 6), bbase + ((t0 + 3) << 6),
                        acc, vs, aBase, bBase, po, wv);
    }
    tile32<false, 0>(&As[0][0], &Bs[0][0], &As[0][0], &Bs[0][0],
                     xbase, bbase, acc, vs, aBase, bBase, po, wv);
    tile32<false, -1>(&As[1][0], &Bs[1][0], &As[1][0], &Bs[1][0],
                      xbase, bbase, acc, vs, aBase, bBase, po, wv);

    // ---- epilogue: logcosh + 32-lane DPP col-reduce; reuse As as scratch ----
    // C/D: col = lane&31, row = (i&3) + 8*(i>>2) + 4*hi. Sum over cols:
    // shr 1/2/4/8 within 16-lane rows, then row_bcast15 add -> lanes 31/63.
    float* rowsum = (float*)&As[0][0];   // [4][256]
    const float bv = bias[lane & 15];    // bias idx = col % 16 = (lane&31)&15
#pragma unroll
    for (int mb = 0; mb < 4; ++mb) {
#pragma unroll
        for (int i = 0; i < 16; ++i) {
            float s = logcosh_fast(acc[mb][0][i] + bv) + logcosh_fast(acc[mb][1][i] + bv);
            s = dppadd<0x111>(s);
            s = dppadd<0x112>(s);
            s = dppadd<0x114>(s);
            s = dppadd<0x118>(s);
            s = dppadd<0x142>(s);   // lane31 += lane15's half-sum (per 32-group)
            if (la31 == 31)
                rowsum[wn * 256 + wm * 128 + mb * 32 + (i & 3) + 8 * (i >> 2) + 4 * hi] = s;
        }
    }
    __syncthreads();
    if (tid < 256) {
        float s = rowsum[tid] + rowsum[256 + tid] + rowsum[512 + tid] + rowsum[768 + tid];
        partial[(size_t)cbx * B + row0 + tid] = s;
    }
}

// ---------- kernel 5: out[b] += sum_cb partial[cb][b] ----------
__global__ __launch_bounds__(256) void k_final(const float* __restrict__ partial,
                                               float* __restrict__ out, int ncb, int B) {
    int b = blockIdx.x * 256 + threadIdx.x;
    float s = out[b];
    for (int c = 0; c < ncb; ++c) s += partial[(size_t)c * B + b];
    out[b] = s;
}

// ---------- launch ----------
extern "C" void kernel_launch(void* const* d_in, const int* in_sizes, int n_in,
                              void* d_out, int out_size, void* d_ws, size_t ws_size,
                              hipStream_t stream) {
    const float* x      = (const float*)d_in[0];  // [B,1024]
    const float* W      = (const float*)d_in[1];  // [1024,16]
    const float* bias   = (const float*)d_in[2];  // [16]
    const float* v_bias = (const float*)d_in[3];  // [1]
    const int*   perms  = (const int*)d_in[4];    // [G,1024]
    float* out = (float*)d_out;

    const int N  = 1024;
    const int B  = in_sizes[0] / N;   // 16384
    const int G  = in_sizes[4] / N;   // 256
    const int GF = G * 16;            // 4096
    const int NCB = GF / 256;         // 16 col blocks

    char* w = (char*)d_ws;
    unsigned short* xb = (unsigned short*)w;                           // B*N*2   = 32 MB
    unsigned short* bT = (unsigned short*)(w + (size_t)B * N * 2);     // GF*N*2  = 8 MB
    int* inv = (int*)(w + (size_t)B * N * 2 + (size_t)GF * N * 2);     // G*N*4   = 1 MB
    float* partial = (float*)(w + (size_t)B * N * 2 + (size_t)GF * N * 2
                              + (size_t)G * N * 4);                    // NCB*B*4 = 1 MB

    k_invert<<<G * N / 256, 256, 0, stream>>>(perms, inv);
    k_build_bt<<<GF, 256, 0, stream>>>(W, inv, bT);
    k_convert<<<B, 256, 0, stream>>>(x, v_bias, xb, out);
    k_gemm<<<dim3(NCB, B / 256), 512, 0, stream>>>(xb, bT, bias, partial, B);
    k_final<<<B / 256, 256, 0, stream>>>(partial, out, NCB, B);
}

// Round 14
// 190.133 us; speedup vs baseline: 1.8723x; 1.0817x over previous
//
#include <hip/hip_runtime.h>
#include <math.h>

typedef __bf16 bf16x8 __attribute__((ext_vector_type(8)));
typedef float f32x4 __attribute__((ext_vector_type(4)));

// ---------- helpers ----------

__device__ __forceinline__ unsigned short f2bf(float f) {
    unsigned int u = __float_as_uint(f);
    u += 0x7FFFu + ((u >> 16) & 1u);   // round-to-nearest-even
    return (unsigned short)(u >> 16);
}

// fast logcosh via HW v_exp/v_log (TRANS pipe). abs err ~1e-6/elem, budget 0.02.
__device__ __forceinline__ float logcosh_fast(float v) {
    float a = fabsf(v);
    float t = __expf(-2.0f * a);
    return a + (__logf(1.0f + t) - 0.6931471805599453f);
}

// DPP row_shr add; after shr 1,2,4,8 lane 15 of each 16-lane row holds row sum.
template <int CTRL>
__device__ __forceinline__ float dppadd(float x) {
    int y = __builtin_amdgcn_update_dpp(0, __float_as_int(x), CTRL, 0xf, 0xf, true);
    return x + __int_as_float(y);
}

__device__ __forceinline__ void gload_lds16(const void* g, void* l) {
    __builtin_amdgcn_global_load_lds(
        (__attribute__((address_space(1))) void*)(void*)g,
        (__attribute__((address_space(3))) void*)l, 16, 0, 0);
}

#define SBAR()  __builtin_amdgcn_s_barrier()
#define SCHED() __builtin_amdgcn_sched_barrier(0)

// ---------- kernel 1: invert permutations ----------
__global__ __launch_bounds__(256) void k_invert(const int* __restrict__ perms,
                                                int* __restrict__ inv) {
    int t = blockIdx.x * 256 + threadIdx.x;
    int g = t >> 10, n = t & 1023;
    inv[(g << 10) + perms[t]] = n;
}

// ---------- kernel 2: bT[j][k] = bf16(W[inv[g][k]][f]), j = g*16+f ----------
__global__ __launch_bounds__(256) void k_build_bt(const float* __restrict__ W,
                                                  const int* __restrict__ inv,
                                                  unsigned short* __restrict__ bT) {
    int j = blockIdx.x;
    int g = j >> 4, f = j & 15;
    const int* invg = inv + (g << 10);
    size_t rowbase = (size_t)j << 10;
#pragma unroll
    for (int i = 0; i < 4; ++i) {
        int k = (i << 8) + threadIdx.x;
        int n = invg[k];
        bT[rowbase + k] = f2bf(W[(n << 4) + f]);
    }
}

// ---------- kernel 3: x -> bf16, out[row] = v_bias * sum(x[row]) ----------
__global__ __launch_bounds__(256) void k_convert(const float* __restrict__ x,
                                                 const float* __restrict__ vb,
                                                 unsigned short* __restrict__ xb,
                                                 float* __restrict__ out) {
    int row = blockIdx.x, tid = threadIdx.x;
    size_t base = ((size_t)row << 10) + (tid << 2);
    float4 v = *reinterpret_cast<const float4*>(x + base);
    ushort4 h;
    h.x = f2bf(v.x); h.y = f2bf(v.y); h.z = f2bf(v.z); h.w = f2bf(v.w);
    *reinterpret_cast<ushort4*>(xb + base) = h;
    float s = v.x + v.y + v.z + v.w;
#pragma unroll
    for (int off = 32; off > 0; off >>= 1) s += __shfl_down(s, off);
    __shared__ float ls[4];
    if ((tid & 63) == 0) ls[tid >> 6] = s;
    __syncthreads();
    if (tid == 0) out[row] = vb[0] * (ls[0] + ls[1] + ls[2] + ls[3]);
}

// ---------- kernel 4: 256x256 GEMM, stage-at-front m-walk, ONE barrier/tile ----
// 8 waves (2m x 4n), per-wave 128x64, acc[8][4], 16x16x32 MFMA (0-conflict
// swizzle). 16 K-tiles BK=64, dbuf. Per tile:
//   front: stage A/B(t+1) -> other buf (8 gload_lds; those bufs' readers all
//          finished before the t-1-end SBAR -> WAR-free with no extra barrier);
//          then 12 ds_reads (8 bF + aF0,aF1)
//   m=0..5: { issue aF[m+2] (2); lgkm(4) -> aF[m] ready; 8 MFMA }
//   m=6: lgkm(2); 8 MFMA.  m=7: lgkm(0); 8 MFMA
//   end: vmcnt(0) [t+1's stages in flight a full tile >= HBM latency -> ~free];
//        SBAR [all waves done reading buf p + t+1 landed]
// Removes R7's mid-tile lgkm(0)+SBAR drain convoy; earliest possible load issue.

#define MFMA_M(MM)                                                               \
    _Pragma("unroll") for (int k_ = 0; k_ < 2; ++k_)                             \
    _Pragma("unroll") for (int n_ = 0; n_ < 4; ++n_)                             \
        acc[MM][n_] = __builtin_amdgcn_mfma_f32_16x16x32_bf16(                   \
            aF[MM][k_], bF[n_][k_], acc[MM][n_], 0, 0, 0);

// stage instr i (of 4) for one 256x64 tile: 512 chunks of 16B, 512 threads
__device__ __forceinline__ void stage_i(unsigned short* dst, const unsigned short* src,
                                        int voff, int i, int wv) {
    gload_lds16(src + voff, dst + (((i << 9) + (wv << 6)) << 3));
}

template <bool ST, int VM>
__device__ __forceinline__ void tile_fs(
    const unsigned short* Ap, const unsigned short* Bp,   // read bufs (tile t)
    unsigned short* AsD, unsigned short* BsD,             // other bufs (t+1 dst)
    const unsigned short* xsrc, const unsigned short* bsrc,   // t+1 global srcs
    f32x4 (&acc)[8][4], const int (&vs)[4],
    int aRow, int bRow, int po0, int po1, int wv) {
    bf16x8 aF[8][2], bF[4][2];

    // front: stage t+1 into the other buffers (WAR-free), then 12 ds_reads
    if (ST) {
#pragma unroll
        for (int i = 0; i < 4; ++i) stage_i(AsD, xsrc, vs[i], i, wv);
#pragma unroll
        for (int i = 0; i < 4; ++i) stage_i(BsD, bsrc, vs[i], i, wv);
    }
    SCHED();
#pragma unroll
    for (int n = 0; n < 4; ++n) {
        bF[n][0] = *reinterpret_cast<const bf16x8*>(Bp + bRow + po0 + n * 1024);
        bF[n][1] = *reinterpret_cast<const bf16x8*>(Bp + bRow + po1 + n * 1024);
    }
#pragma unroll
    for (int m = 0; m < 2; ++m) {
        aF[m][0] = *reinterpret_cast<const bf16x8*>(Ap + aRow + po0 + m * 1024);
        aF[m][1] = *reinterpret_cast<const bf16x8*>(Ap + aRow + po1 + m * 1024);
    }
    SCHED();

    // m=0..5: prefetch aF[m+2], counted lgkm, 8 MFMA
#pragma unroll
    for (int m = 0; m < 6; ++m) {
        aF[m + 2][0] = *reinterpret_cast<const bf16x8*>(Ap + aRow + po0 + (m + 2) * 1024);
        aF[m + 2][1] = *reinterpret_cast<const bf16x8*>(Ap + aRow + po1 + (m + 2) * 1024);
        SCHED();
        asm volatile("s_waitcnt lgkmcnt(4)" ::: "memory");
        SCHED();
        __builtin_amdgcn_s_setprio(1);
        MFMA_M(m)
        __builtin_amdgcn_s_setprio(0);
        SCHED();
    }
    // m=6: aF[6] ready at lgkm(2)
    asm volatile("s_waitcnt lgkmcnt(2)" ::: "memory");
    SCHED();
    __builtin_amdgcn_s_setprio(1);
    MFMA_M(6)
    __builtin_amdgcn_s_setprio(0);
    SCHED();
    // m=7: aF[7] ready at lgkm(0)
    asm volatile("s_waitcnt lgkmcnt(0)" ::: "memory");
    SCHED();
    __builtin_amdgcn_s_setprio(1);
    MFMA_M(7)
    __builtin_amdgcn_s_setprio(0);
    SCHED();
    if (VM == 0) { asm volatile("s_waitcnt vmcnt(0)" ::: "memory"); }
    SCHED();
    SBAR();
}

__global__ __launch_bounds__(512, 2) void k_gemm(const unsigned short* __restrict__ xb,
                                                 const unsigned short* __restrict__ bT,
                                                 const float* __restrict__ bias,
                                                 float* __restrict__ partial, int B) {
    __shared__ unsigned short As[2][256 * 64];
    __shared__ unsigned short Bs[2][256 * 64];

    const int tid = threadIdx.x;
    const int lane = tid & 63;
    const int wv = tid >> 6;           // 0..7
    const int wm = wv >> 2;            // 0..1  (M half)
    const int wn = wv & 3;             // 0..3  (N quarter)
    const int lr = lane & 15;
    const int lk = lane >> 4;

    // XCD-bijective swizzle (nwg = 1024, % 8 == 0)
    const int fid = blockIdx.y * gridDim.x + blockIdx.x;
    const int cpx = (gridDim.x * gridDim.y) >> 3;
    const int swz = (fid & 7) * cpx + (fid >> 3);
    const int cbx = swz & 15;          // col block (0..15)
    const int row0 = (swz >> 4) << 8;  // row block * 256
    const int j0 = cbx << 8;

    const unsigned short* xbase = xb + ((size_t)row0 << 10);
    const unsigned short* bbase = bT + ((size_t)j0 << 10);

    // per-wave LDS read bases (short units); +m*1024 imm offsets
    const int aRow = (wm * 128 + lr) * 64;
    const int bRow = (wn * 64 + lr) * 64;
    const int po0 = (lk ^ (lr & 7)) * 8;
    const int po1 = ((4 + lk) ^ (lr & 7)) * 8;

    // per-thread stage source voffsets (shorts); instr i covers chunks i*512+tid
    int vs[4];
#pragma unroll
    for (int i = 0; i < 4; ++i) {
        int cc = (i << 9) + tid;
        int r = cc >> 3;
        int cs = (cc & 7) ^ (r & 7);
        vs[i] = (r << 10) + (cs << 3);
    }

    f32x4 acc[8][4];
#pragma unroll
    for (int m = 0; m < 8; ++m)
#pragma unroll
        for (int n = 0; n < 4; ++n)
            acc[m][n] = {0.f, 0.f, 0.f, 0.f};

    // ---- prologue: stage tile0(A,B) + tile1(A,B); wait tile0; SBAR ----
#pragma unroll
    for (int i = 0; i < 4; ++i) stage_i(&As[0][0], xbase, vs[i], i, wv);
#pragma unroll
    for (int i = 0; i < 4; ++i) stage_i(&Bs[0][0], bbase, vs[i], i, wv);
#pragma unroll
    for (int i = 0; i < 4; ++i) stage_i(&As[1][0], xbase + 64, vs[i], i, wv);
#pragma unroll
    for (int i = 0; i < 4; ++i) stage_i(&Bs[1][0], bbase + 64, vs[i], i, wv);
    asm volatile("s_waitcnt vmcnt(8)" ::: "memory");   // tile0 landed
    SCHED();
    SBAR();

    // ---- t=0: tile1 already prestaged (in flight; drained by t0-end vmcnt(0))
    tile_fs<false, 0>(&As[0][0], &Bs[0][0], &As[1][0], &Bs[1][0],
                      xbase, bbase, acc, vs, aRow, bRow, po0, po1, wv);
    // ---- t=1..14: front-stage t+1 into the other buffers ----
    for (int tt = 0; tt < 7; ++tt) {
        const int t = 2 * tt + 1;   // odd tile: read buf1, stage t+1 -> buf0
        tile_fs<true, 0>(&As[1][0], &Bs[1][0], &As[0][0], &Bs[0][0],
                         xbase + ((t + 1) << 6), bbase + ((t + 1) << 6),
                         acc, vs, aRow, bRow, po0, po1, wv);
        // even tile t+1: read buf0, stage t+2 -> buf1
        tile_fs<true, 0>(&As[0][0], &Bs[0][0], &As[1][0], &Bs[1][0],
                         xbase + ((t + 2) << 6), bbase + ((t + 2) << 6),
                         acc, vs, aRow, bRow, po0, po1, wv);
    }
    // ---- t=15: nothing to stage or wait on ----
    tile_fs<false, -1>(&As[1][0], &Bs[1][0], &As[0][0], &Bs[0][0],
                       xbase, bbase, acc, vs, aRow, bRow, po0, po1, wv);

    // ---- epilogue: fast logcosh + DPP row-reduce; reuse As as scratch ----
    float* rowsum = (float*)&As[0][0];   // [4][256]
    const float bv = bias[lr];           // C col % 16 == lane&15
#pragma unroll
    for (int m = 0; m < 8; ++m) {
#pragma unroll
        for (int r = 0; r < 4; ++r) {
            float s = 0.f;
#pragma unroll
            for (int n = 0; n < 4; ++n) s += logcosh_fast(acc[m][n][r] + bv);
            s = dppadd<0x111>(s);
            s = dppadd<0x112>(s);
            s = dppadd<0x114>(s);
            s = dppadd<0x118>(s);
            if (lr == 15)
                rowsum[wn * 256 + wm * 128 + m * 16 + lk * 4 + r] = s;
        }
    }
    __syncthreads();
    if (tid < 256) {
        float s = rowsum[tid] + rowsum[256 + tid] + rowsum[512 + tid] + rowsum[768 + tid];
        partial[(size_t)cbx * B + row0 + tid] = s;
    }
}

// ---------- kernel 5: out[b] += sum_cb partial[cb][b] ----------
__global__ __launch_bounds__(256) void k_final(const float* __restrict__ partial,
                                               float* __restrict__ out, int ncb, int B) {
    int b = blockIdx.x * 256 + threadIdx.x;
    float s = out[b];
    for (int c = 0; c < ncb; ++c) s += partial[(size_t)c * B + b];
    out[b] = s;
}

// ---------- launch ----------
extern "C" void kernel_launch(void* const* d_in, const int* in_sizes, int n_in,
                              void* d_out, int out_size, void* d_ws, size_t ws_size,
                              hipStream_t stream) {
    const float* x      = (const float*)d_in[0];  // [B,1024]
    const float* W      = (const float*)d_in[1];  // [1024,16]
    const float* bias   = (const float*)d_in[2];  // [16]
    const float* v_bias = (const float*)d_in[3];  // [1]
    const int*   perms  = (const int*)d_in[4];    // [G,1024]
    float* out = (float*)d_out;

    const int N  = 1024;
    const int B  = in_sizes[0] / N;   // 16384
    const int G  = in_sizes[4] / N;   // 256
    const int GF = G * 16;            // 4096
    const int NCB = GF / 256;         // 16 col blocks

    char* w = (char*)d_ws;
    unsigned short* xb = (unsigned short*)w;                           // B*N*2   = 32 MB
    unsigned short* bT = (unsigned short*)(w + (size_t)B * N * 2);     // GF*N*2  = 8 MB
    int* inv = (int*)(w + (size_t)B * N * 2 + (size_t)GF * N * 2);     // G*N*4   = 1 MB
    float* partial = (float*)(w + (size_t)B * N * 2 + (size_t)GF * N * 2
                              + (size_t)G * N * 4);                    // NCB*B*4 = 1 MB

    k_invert<<<G * N / 256, 256, 0, stream>>>(perms, inv);
    k_build_bt<<<GF, 256, 0, stream>>>(W, inv, bT);
    k_convert<<<B, 256, 0, stream>>>(x, v_bias, xb, out);
    k_gemm<<<dim3(NCB, B / 256), 512, 0, stream>>>(xb, bT, bias, partial, B);
    k_final<<<B / 256, 256, 0, stream>>>(partial, out, NCB, B);
}